// Round 5
// baseline (215.202 us; speedup 1.0000x reference)
//
#include <hip/hip_runtime.h>
#include <math.h>

#define BB 64
#define LL 1024
#define HH 256
#define TT 128
#define D_ID 128
#define D_SZ 64
#define D_POS 128
#define DX 192   // D_ID + D_SZ

typedef short s16x8 __attribute__((ext_vector_type(8)));
typedef float f32x16 __attribute__((ext_vector_type(16)));
typedef unsigned short u16x8 __attribute__((ext_vector_type(8)));

__device__ __forceinline__ unsigned short f2bf(float f) {
    unsigned u = __float_as_uint(f);
    unsigned r = u + 0x7fffu + ((u >> 16) & 1u);   // RNE
    return (unsigned short)(r >> 16);
}

__device__ __forceinline__ s16x8 pack8(float4 a, float4 b) {
    u16x8 p;
    p[0] = f2bf(a.x); p[1] = f2bf(a.y); p[2] = f2bf(a.z); p[3] = f2bf(a.w);
    p[4] = f2bf(b.x); p[5] = f2bf(b.y); p[6] = f2bf(b.z); p[7] = f2bf(b.w);
    return (s16x8)p;
}

// ------------------------------------------- xh_t[448][64] = concat(x, h0)^T
__global__ void embed_kernel(const int* __restrict__ obj_id,
                             const int* __restrict__ obj_size,
                             const float* __restrict__ h0,
                             const float* __restrict__ obj_id_table,
                             const float* __restrict__ obj_size_table,
                             float* __restrict__ xh_t) {
    int tid = threadIdx.x;
    int b = tid & 63;
    int k = blockIdx.x * 4 + (tid >> 6);
    float v;
    if (k < D_ID)      v = obj_id_table[(size_t)obj_id[b] * D_ID + k];
    else if (k < DX)   v = obj_size_table[(size_t)obj_size[b] * D_SZ + (k - D_ID)];
    else               v = h0[b * HH + (k - DX)];
    xh_t[k * 64 + b] = v;
}

// --------------- gates + fused LSTM activation
// grid 256 (one j per block), block 256: wave q owns W row q*HH+j
// (wave-uniform -> scalar loads); xh_t read k-major, coalesced across b lanes.
__global__ void gates_kernel(const float* __restrict__ xh_t,
                             const float* __restrict__ W_ih,
                             const float* __restrict__ W_hh,
                             const float* __restrict__ b_ih,
                             const float* __restrict__ b_hh,
                             const float* __restrict__ c0,
                             float* __restrict__ h_new) {
    int j = blockIdx.x;
    int tid = threadIdx.x;
    int b = tid & 63;
    int q = __builtin_amdgcn_readfirstlane(tid >> 6);
    int r = q * HH + j;
    __shared__ float gS[256];

    float acc = b_ih[r] + b_hh[r];
    const float* wi = W_ih + (size_t)r * DX;
    const float* wh = W_hh + (size_t)r * HH;
#pragma unroll 16
    for (int k = 0; k < DX; ++k)
        acc += wi[k] * xh_t[k * 64 + b];
#pragma unroll 16
    for (int k = 0; k < HH; ++k)
        acc += wh[k] * xh_t[(DX + k) * 64 + b];
    gS[q * 64 + b] = acc;
    __syncthreads();

    if (tid < 64) {
        float ig = 1.f / (1.f + expf(-gS[tid]));
        float fg = 1.f / (1.f + expf(-gS[64 + tid]));
        float gg = tanhf(gS[128 + tid]);
        float og = 1.f / (1.f + expf(-gS[192 + tid]));
        float c = fg * c0[tid * HH + j] + ig * gg;
        h_new[tid * HH + j] = og * tanhf(c);
    }
}

// ------------- fused: HP(bf16) = hist @ attn_W^T (MFMA)  +  sv/rv dots
// grid: B*16 proj blocks (1 wave) + B*4 svrv blocks, block 64.
__global__ void proj_kernel(const float* __restrict__ history,
                            const float* __restrict__ h_new,
                            const float* __restrict__ attn_W,
                            const float* __restrict__ pos_table,
                            const float* __restrict__ scorer_W,
                            const float* __restrict__ reuse_W,
                            unsigned short* __restrict__ hp,
                            float* __restrict__ sv,
                            float* __restrict__ rv,
                            int* __restrict__ cnt) {
    int blk = blockIdx.x;
    int tid = threadIdx.x;

    if (blk >= BB * 16) {
        // ---- svrv part: idx = b*4 + which*2 + thalf
        int idx = blk - BB * 16;
        if (idx == 0) cnt[tid] = 0;            // zero last-block counters
        int b = idx >> 2;
        int which = (idx >> 1) & 1;
        int t = (idx & 1) * 64 + tid;
        const float* w = which ? reuse_W : scorer_W;
        const float* hrow = (t < TT - 1)
            ? history + ((size_t)b * (TT - 1) + t) * HH
            : h_new + (size_t)b * HH;
        float acc = 0.f;
#pragma unroll 8
        for (int k = 0; k < HH / 4; ++k) {
            float4 hv = *(const float4*)(hrow + 4 * k);
            float4 wv = *(const float4*)(w + 4 * k);
            acc += hv.x * wv.x + hv.y * wv.y + hv.z * wv.z + hv.w * wv.w;
        }
        const float* prow = pos_table + (size_t)t * D_POS;
#pragma unroll 8
        for (int k = 0; k < D_POS / 4; ++k) {
            float4 pv = *(const float4*)(prow + 4 * k);
            float4 wv = *(const float4*)(w + HH + 4 * k);
            acc += pv.x * wv.x + pv.y * wv.y + pv.z * wv.z + pv.w * wv.w;
        }
        (which ? rv : sv)[b * TT + t] = acc;
        return;
    }

    // ---- proj part: one wave, direct-from-global MFMA fragments
    int b  = blk >> 4;
    int t0 = ((blk >> 2) & 3) * 32;
    int d0 = (blk & 3) * 32;
    int lane = tid;
    int ln = lane & 31, half = lane >> 5;

    int t = t0 + ln;
    const float* arow = (t < TT - 1)
        ? history + ((size_t)b * (TT - 1) + t) * HH
        : h_new + (size_t)b * HH;
    const float* brow = attn_W + (size_t)(d0 + ln) * HH;

    f32x16 acc;
#pragma unroll
    for (int r = 0; r < 16; ++r) acc[r] = 0.f;

#pragma unroll
    for (int ks = 0; ks < 16; ++ks) {
        int off = ks * 16 + half * 8;
        float4 a0 = *(const float4*)(arow + off);
        float4 a1 = *(const float4*)(arow + off + 4);
        float4 b0 = *(const float4*)(brow + off);
        float4 b1 = *(const float4*)(brow + off + 4);
        acc = __builtin_amdgcn_mfma_f32_32x32x16_bf16(
            pack8(a0, a1), pack8(b0, b1), acc, 0, 0, 0);
    }

#pragma unroll
    for (int r = 0; r < 16; ++r) {
        int tt = t0 + (r & 3) + 8 * (r >> 2) + 4 * half;
        hp[((size_t)b * TT + tt) * D_ID + d0 + ln] = f2bf(acc[r]);
    }
}

// ---- scores = Q@HP^T (MFMA), softmax over t, heads; last block per batch
//      also runs the masked softmax over L (fused finalsm).
// grid: B*8 (128-l tiles), block 256 (4 waves)
__global__ void attn_kernel(const int* __restrict__ cache_lines,
                            const float* __restrict__ obj_id_table,
                            const unsigned short* __restrict__ hp,
                            const float* __restrict__ sv,
                            const float* __restrict__ rv,
                            const float* __restrict__ scorer_b,
                            const float* __restrict__ reuse_b,
                            const int* __restrict__ lengths,
                            float* __restrict__ logits,
                            float* __restrict__ out_probs,
                            float* __restrict__ out_reuse,
                            int* __restrict__ cnt) {
    int b  = blockIdx.x >> 3;
    int l0 = (blockIdx.x & 7) * 128;
    int tid = threadIdx.x;
    __shared__ unsigned short qS[16384];   // [w][k][lane][8]
    __shared__ unsigned short hpS[16384];  // [k][tt][lane][8]
    __shared__ int lastFlag;
    __shared__ float redm[4];
    __shared__ float reds[4];

    {
        int l = tid & 127;
        int cl = cache_lines[b * LL + l0 + l];
        const float* qrow = obj_id_table + (size_t)cl * D_ID;
        int lhi = (l >> 5) * 8, llo = l & 31;
#pragma unroll
        for (int i = 0; i < 8; ++i) {
            int u = 2 * i + (tid >> 7);
            float4 f0 = *(const float4*)(qrow + u * 8);
            float4 f1 = *(const float4*)(qrow + u * 8 + 4);
            *(s16x8*)(qS + (((lhi + (u >> 1)) * 64) + (u & 1) * 32 + llo) * 8) =
                pack8(f0, f1);
        }
    }
    {
        int t = tid & 127;
        const unsigned short* hrow = hp + ((size_t)b * TT + t) * D_ID;
        int thi = t >> 5, tlo = t & 31;
#pragma unroll
        for (int i = 0; i < 8; ++i) {
            int u = 2 * i + (tid >> 7);
            u16x8 p = *(const u16x8*)(hrow + u * 8);
            *(u16x8*)(hpS + ((((u >> 1) * 4 + thi) * 64) + (u & 1) * 32 + tlo) * 8) = p;
        }
    }
    __syncthreads();

    int w = tid >> 6;
    int lane = tid & 63;
    int ln = lane & 31, half = lane >> 5;

    f32x16 acc[4];
#pragma unroll
    for (int tt = 0; tt < 4; ++tt)
#pragma unroll
        for (int r = 0; r < 16; ++r) acc[tt][r] = 0.f;

    const unsigned short* qw = qS + w * 8 * 512;
#pragma unroll
    for (int k = 0; k < 8; ++k) {
        s16x8 a = *(const s16x8*)(qw + k * 512 + lane * 8);
#pragma unroll
        for (int tt = 0; tt < 4; ++tt) {
            s16x8 bf = *(const s16x8*)(hpS + (k * 4 + tt) * 512 + lane * 8);
            acc[tt] = __builtin_amdgcn_mfma_f32_32x32x16_bf16(a, bf, acc[tt], 0, 0, 0);
        }
    }

    float sv_r[4], rv_r[4];
#pragma unroll
    for (int tt = 0; tt < 4; ++tt) {
        sv_r[tt] = sv[b * TT + tt * 32 + ln];
        rv_r[tt] = rv[b * TT + tt * 32 + ln];
    }
    float sb = scorer_b[0], rb = reuse_b[0];

#pragma unroll
    for (int r = 0; r < 16; ++r) {
        float v0 = acc[0][r], v1 = acc[1][r], v2 = acc[2][r], v3 = acc[3][r];
        float m = fmaxf(fmaxf(v0, v1), fmaxf(v2, v3));
#pragma unroll
        for (int off = 1; off < 32; off <<= 1) m = fmaxf(m, __shfl_xor(m, off));
        float e0 = __expf(v0 - m), e1 = __expf(v1 - m),
              e2 = __expf(v2 - m), e3 = __expf(v3 - m);
        float s  = e0 + e1 + e2 + e3;
        float lg = e0 * sv_r[0] + e1 * sv_r[1] + e2 * sv_r[2] + e3 * sv_r[3];
        float rg = e0 * rv_r[0] + e1 * rv_r[1] + e2 * rv_r[2] + e3 * rv_r[3];
#pragma unroll
        for (int off = 1; off < 32; off <<= 1) {
            s  += __shfl_xor(s, off);
            lg += __shfl_xor(lg, off);
            rg += __shfl_xor(rg, off);
        }
        if (ln == 0) {
            int row = (r & 3) + 8 * (r >> 2) + 4 * half;
            int l = l0 + w * 32 + row;
            logits[b * LL + l] = lg / s + sb;
            out_reuse[b * LL + l] = rg / s + rb;
        }
    }

    // ---- last block for this batch runs the masked softmax over L
    __threadfence();                       // publish logits (device scope)
    __syncthreads();
    if (tid == 0) lastFlag = (atomicAdd(&cnt[b], 1) == 7);
    __syncthreads();
    if (!lastFlag) return;
    __threadfence();                       // acquire other blocks' logits

    int valid = max(lengths[b], 1);
    float v[4];
    float m = -1e30f;
#pragma unroll
    for (int i = 0; i < 4; ++i) {
        int l = tid + 256 * i;
        v[i] = (l < valid) ? logits[b * LL + l] : -1e30f;
        m = fmaxf(m, v[i]);
    }
#pragma unroll
    for (int off = 1; off < 64; off <<= 1) m = fmaxf(m, __shfl_xor(m, off));
    int wave = tid >> 6;
    if ((tid & 63) == 0) redm[wave] = m;
    __syncthreads();
    m = fmaxf(fmaxf(redm[0], redm[1]), fmaxf(redm[2], redm[3]));
    float e[4];
    float s = 0.f;
#pragma unroll
    for (int i = 0; i < 4; ++i) {
        int l = tid + 256 * i;
        e[i] = (l < valid) ? expf(v[i] - m) : 0.f;
        s += e[i];
    }
#pragma unroll
    for (int off = 1; off < 64; off <<= 1) s += __shfl_xor(s, off);
    if ((tid & 63) == 0) reds[wave] = s;
    __syncthreads();
    s = reds[0] + reds[1] + reds[2] + reds[3];
    float inv = 1.f / s;
#pragma unroll
    for (int i = 0; i < 4; ++i)
        out_probs[b * LL + tid + 256 * i] = e[i] * inv;
}

extern "C" void kernel_launch(void* const* d_in, const int* in_sizes, int n_in,
                              void* d_out, int out_size, void* d_ws, size_t ws_size,
                              hipStream_t stream) {
    const int*   obj_id         = (const int*)d_in[0];
    const int*   obj_size       = (const int*)d_in[1];
    const int*   cache_lines    = (const int*)d_in[2];
    const int*   lengths        = (const int*)d_in[3];
    const float* c0             = (const float*)d_in[4];
    const float* h0             = (const float*)d_in[5];
    const float* history        = (const float*)d_in[6];
    const float* obj_id_table   = (const float*)d_in[7];
    const float* obj_size_table = (const float*)d_in[8];
    const float* pos_table      = (const float*)d_in[9];
    const float* W_ih           = (const float*)d_in[10];
    const float* W_hh           = (const float*)d_in[11];
    const float* b_ih           = (const float*)d_in[12];
    const float* b_hh           = (const float*)d_in[13];
    const float* attn_W         = (const float*)d_in[14];
    const float* scorer_W       = (const float*)d_in[15];
    const float* scorer_b       = (const float*)d_in[16];
    const float* reuse_W        = (const float*)d_in[17];
    const float* reuse_b        = (const float*)d_in[18];

    float* out = (float*)d_out;
    float* out_probs = out;                 // (B, L)
    float* out_reuse = out + BB * LL;       // (B, L)

    char* ws = (char*)d_ws;
    float*          h_new  = (float*)(ws);                    // 64 KB
    unsigned short* hp     = (unsigned short*)(ws + 65536);   // 2 MB bf16
    float*          sv     = (float*)(ws + 65536 + 2097152);
    float*          rv     = (float*)(ws + 65536 + 2097152 + 32768);
    float*          xh_t   = (float*)(ws + 65536 + 2097152 + 65536);  // 112 KB
    float*          logits = (float*)(ws + 65536 + 2097152 + 65536);  // shares (disjoint lifetime)
    int*            cnt    = (int*)(ws + 65536 + 2097152 + 65536 + 262144); // 64 ints

    hipLaunchKernelGGL(embed_kernel, dim3(112), dim3(256), 0, stream,
                       obj_id, obj_size, h0, obj_id_table, obj_size_table, xh_t);
    hipLaunchKernelGGL(gates_kernel, dim3(HH), dim3(256), 0, stream,
                       xh_t, W_ih, W_hh, b_ih, b_hh, c0, h_new);
    hipLaunchKernelGGL(proj_kernel, dim3(BB * 16 + BB * 4), dim3(64), 0, stream,
                       history, h_new, attn_W, pos_table, scorer_W, reuse_W,
                       hp, sv, rv, cnt);
    hipLaunchKernelGGL(attn_kernel, dim3(BB * 8), dim3(256), 0, stream,
                       cache_lines, obj_id_table, hp, sv, rv,
                       scorer_b, reuse_b, lengths, logits, out_probs, out_reuse, cnt);
}

// Round 6
// 160.936 us; speedup vs baseline: 1.3372x; 1.3372x over previous
//
#include <hip/hip_runtime.h>
#include <math.h>

#define BB 64
#define LL 1024
#define HH 256
#define TT 128
#define D_ID 128
#define D_SZ 64
#define D_POS 128
#define DX 192   // D_ID + D_SZ

typedef short s16x8 __attribute__((ext_vector_type(8)));
typedef float f32x16 __attribute__((ext_vector_type(16)));
typedef unsigned short u16x8 __attribute__((ext_vector_type(8)));

__device__ __forceinline__ unsigned short f2bf(float f) {
    unsigned u = __float_as_uint(f);
    unsigned r = u + 0x7fffu + ((u >> 16) & 1u);   // RNE
    return (unsigned short)(r >> 16);
}

__device__ __forceinline__ s16x8 pack8(float4 a, float4 b) {
    u16x8 p;
    p[0] = f2bf(a.x); p[1] = f2bf(a.y); p[2] = f2bf(a.z); p[3] = f2bf(a.w);
    p[4] = f2bf(b.x); p[5] = f2bf(b.y); p[6] = f2bf(b.z); p[7] = f2bf(b.w);
    return (s16x8)p;
}

// ------------------------------------------- xh_t[448][64] = concat(x, h0)^T
__global__ void embed_kernel(const int* __restrict__ obj_id,
                             const int* __restrict__ obj_size,
                             const float* __restrict__ h0,
                             const float* __restrict__ obj_id_table,
                             const float* __restrict__ obj_size_table,
                             float* __restrict__ xh_t) {
    int tid = threadIdx.x;
    int b = tid & 63;
    int k = blockIdx.x * 4 + (tid >> 6);
    float v;
    if (k < D_ID)      v = obj_id_table[(size_t)obj_id[b] * D_ID + k];
    else if (k < DX)   v = obj_size_table[(size_t)obj_size[b] * D_SZ + (k - D_ID)];
    else               v = h0[b * HH + (k - DX)];
    xh_t[k * 64 + b] = v;
}

// --------------- gates + fused LSTM activation
// grid 256 (one j per block), block 256: wave q owns W row q*HH+j
// (wave-uniform -> scalar loads); xh_t read k-major, coalesced across b lanes.
__global__ void gates_kernel(const float* __restrict__ xh_t,
                             const float* __restrict__ W_ih,
                             const float* __restrict__ W_hh,
                             const float* __restrict__ b_ih,
                             const float* __restrict__ b_hh,
                             const float* __restrict__ c0,
                             float* __restrict__ h_new) {
    int j = blockIdx.x;
    int tid = threadIdx.x;
    int b = tid & 63;
    int q = __builtin_amdgcn_readfirstlane(tid >> 6);
    int r = q * HH + j;
    __shared__ float gS[256];

    float acc = b_ih[r] + b_hh[r];
    const float* wi = W_ih + (size_t)r * DX;
    const float* wh = W_hh + (size_t)r * HH;
#pragma unroll 16
    for (int k = 0; k < DX; ++k)
        acc += wi[k] * xh_t[k * 64 + b];
#pragma unroll 16
    for (int k = 0; k < HH; ++k)
        acc += wh[k] * xh_t[(DX + k) * 64 + b];
    gS[q * 64 + b] = acc;
    __syncthreads();

    if (tid < 64) {
        float ig = 1.f / (1.f + expf(-gS[tid]));
        float fg = 1.f / (1.f + expf(-gS[64 + tid]));
        float gg = tanhf(gS[128 + tid]);
        float og = 1.f / (1.f + expf(-gS[192 + tid]));
        float c = fg * c0[tid * HH + j] + ig * gg;
        h_new[tid * HH + j] = og * tanhf(c);
    }
}

// ------------- fused: HP(bf16) = hist @ attn_W^T (MFMA)  +  sv/rv dots
// grid: B*16 proj blocks (1 wave) + B*4 svrv blocks, block 64.
__global__ void proj_kernel(const float* __restrict__ history,
                            const float* __restrict__ h_new,
                            const float* __restrict__ attn_W,
                            const float* __restrict__ pos_table,
                            const float* __restrict__ scorer_W,
                            const float* __restrict__ reuse_W,
                            unsigned short* __restrict__ hp,
                            float* __restrict__ sv,
                            float* __restrict__ rv) {
    int blk = blockIdx.x;
    int tid = threadIdx.x;

    if (blk >= BB * 16) {
        // ---- svrv part: idx = b*4 + which*2 + thalf
        int idx = blk - BB * 16;
        int b = idx >> 2;
        int which = (idx >> 1) & 1;
        int t = (idx & 1) * 64 + tid;
        const float* w = which ? reuse_W : scorer_W;
        const float* hrow = (t < TT - 1)
            ? history + ((size_t)b * (TT - 1) + t) * HH
            : h_new + (size_t)b * HH;
        float acc = 0.f;
#pragma unroll 8
        for (int k = 0; k < HH / 4; ++k) {
            float4 hv = *(const float4*)(hrow + 4 * k);
            float4 wv = *(const float4*)(w + 4 * k);
            acc += hv.x * wv.x + hv.y * wv.y + hv.z * wv.z + hv.w * wv.w;
        }
        const float* prow = pos_table + (size_t)t * D_POS;
#pragma unroll 8
        for (int k = 0; k < D_POS / 4; ++k) {
            float4 pv = *(const float4*)(prow + 4 * k);
            float4 wv = *(const float4*)(w + HH + 4 * k);
            acc += pv.x * wv.x + pv.y * wv.y + pv.z * wv.z + pv.w * wv.w;
        }
        (which ? rv : sv)[b * TT + t] = acc;
        return;
    }

    // ---- proj part: one wave, direct-from-global MFMA fragments
    int b  = blk >> 4;
    int t0 = ((blk >> 2) & 3) * 32;
    int d0 = (blk & 3) * 32;
    int lane = tid;
    int ln = lane & 31, half = lane >> 5;

    int t = t0 + ln;
    const float* arow = (t < TT - 1)
        ? history + ((size_t)b * (TT - 1) + t) * HH
        : h_new + (size_t)b * HH;
    const float* brow = attn_W + (size_t)(d0 + ln) * HH;

    f32x16 acc;
#pragma unroll
    for (int r = 0; r < 16; ++r) acc[r] = 0.f;

#pragma unroll
    for (int ks = 0; ks < 16; ++ks) {
        int off = ks * 16 + half * 8;
        float4 a0 = *(const float4*)(arow + off);
        float4 a1 = *(const float4*)(arow + off + 4);
        float4 b0 = *(const float4*)(brow + off);
        float4 b1 = *(const float4*)(brow + off + 4);
        acc = __builtin_amdgcn_mfma_f32_32x32x16_bf16(
            pack8(a0, a1), pack8(b0, b1), acc, 0, 0, 0);
    }

#pragma unroll
    for (int r = 0; r < 16; ++r) {
        int tt = t0 + (r & 3) + 8 * (r >> 2) + 4 * half;
        hp[((size_t)b * TT + tt) * D_ID + d0 + ln] = f2bf(acc[r]);
    }
}

// ---- scores = Q@HP^T via mfma_32x32x16_bf16, softmax over t, heads
// grid: B*8 (128-l tiles), block 256 (4 waves; wave w owns 32 l-rows)
// NOTE: no cross-block fences here — R5 showed __threadfence() in every
// block costs ~70 µs (TCC serialization). finalsm is a separate dispatch.
__global__ void attn_kernel(const int* __restrict__ cache_lines,
                            const float* __restrict__ obj_id_table,
                            const unsigned short* __restrict__ hp,
                            const float* __restrict__ sv,
                            const float* __restrict__ rv,
                            const float* __restrict__ scorer_b,
                            const float* __restrict__ reuse_b,
                            float* __restrict__ logits,
                            float* __restrict__ out_reuse) {
    int b  = blockIdx.x >> 3;
    int l0 = (blockIdx.x & 7) * 128;
    int tid = threadIdx.x;
    __shared__ unsigned short qS[16384];   // [w][k][lane][8]
    __shared__ unsigned short hpS[16384];  // [k][tt][lane][8]

    {
        int l = tid & 127;
        int cl = cache_lines[b * LL + l0 + l];
        const float* qrow = obj_id_table + (size_t)cl * D_ID;
        int lhi = (l >> 5) * 8, llo = l & 31;
#pragma unroll
        for (int i = 0; i < 8; ++i) {
            int u = 2 * i + (tid >> 7);
            float4 f0 = *(const float4*)(qrow + u * 8);
            float4 f1 = *(const float4*)(qrow + u * 8 + 4);
            *(s16x8*)(qS + (((lhi + (u >> 1)) * 64) + (u & 1) * 32 + llo) * 8) =
                pack8(f0, f1);
        }
    }
    {
        int t = tid & 127;
        const unsigned short* hrow = hp + ((size_t)b * TT + t) * D_ID;
        int thi = t >> 5, tlo = t & 31;
#pragma unroll
        for (int i = 0; i < 8; ++i) {
            int u = 2 * i + (tid >> 7);
            u16x8 p = *(const u16x8*)(hrow + u * 8);
            *(u16x8*)(hpS + ((((u >> 1) * 4 + thi) * 64) + (u & 1) * 32 + tlo) * 8) = p;
        }
    }
    __syncthreads();

    int w = tid >> 6;
    int lane = tid & 63;
    int ln = lane & 31, half = lane >> 5;

    f32x16 acc[4];
#pragma unroll
    for (int tt = 0; tt < 4; ++tt)
#pragma unroll
        for (int r = 0; r < 16; ++r) acc[tt][r] = 0.f;

    const unsigned short* qw = qS + w * 8 * 512;
#pragma unroll
    for (int k = 0; k < 8; ++k) {
        s16x8 a = *(const s16x8*)(qw + k * 512 + lane * 8);
#pragma unroll
        for (int tt = 0; tt < 4; ++tt) {
            s16x8 bf = *(const s16x8*)(hpS + (k * 4 + tt) * 512 + lane * 8);
            acc[tt] = __builtin_amdgcn_mfma_f32_32x32x16_bf16(a, bf, acc[tt], 0, 0, 0);
        }
    }

    float sv_r[4], rv_r[4];
#pragma unroll
    for (int tt = 0; tt < 4; ++tt) {
        sv_r[tt] = sv[b * TT + tt * 32 + ln];
        rv_r[tt] = rv[b * TT + tt * 32 + ln];
    }
    float sb = scorer_b[0], rb = reuse_b[0];

#pragma unroll
    for (int r = 0; r < 16; ++r) {
        float v0 = acc[0][r], v1 = acc[1][r], v2 = acc[2][r], v3 = acc[3][r];
        float m = fmaxf(fmaxf(v0, v1), fmaxf(v2, v3));
#pragma unroll
        for (int off = 1; off < 32; off <<= 1) m = fmaxf(m, __shfl_xor(m, off));
        float e0 = __expf(v0 - m), e1 = __expf(v1 - m),
              e2 = __expf(v2 - m), e3 = __expf(v3 - m);
        float s  = e0 + e1 + e2 + e3;
        float lg = e0 * sv_r[0] + e1 * sv_r[1] + e2 * sv_r[2] + e3 * sv_r[3];
        float rg = e0 * rv_r[0] + e1 * rv_r[1] + e2 * rv_r[2] + e3 * rv_r[3];
#pragma unroll
        for (int off = 1; off < 32; off <<= 1) {
            s  += __shfl_xor(s, off);
            lg += __shfl_xor(lg, off);
            rg += __shfl_xor(rg, off);
        }
        if (ln == 0) {
            int row = (r & 3) + 8 * (r >> 2) + 4 * half;
            int l = l0 + w * 32 + row;
            logits[b * LL + l] = lg / s + sb;
            out_reuse[b * LL + l] = rg / s + rb;
        }
    }
}

// -------------------------------------- masked softmax over L per batch
__global__ void finalsm_kernel(const float* __restrict__ logits,
                               const int* __restrict__ lengths,
                               float* __restrict__ out_probs) {
    int b = blockIdx.x;
    int tid = threadIdx.x;
    int valid = max(lengths[b], 1);
    float v[4];
    float m = -1e30f;
#pragma unroll
    for (int i = 0; i < 4; ++i) {
        int l = tid + 256 * i;
        v[i] = (l < valid) ? logits[b * LL + l] : -1e30f;
        m = fmaxf(m, v[i]);
    }
#pragma unroll
    for (int off = 1; off < 64; off <<= 1) m = fmaxf(m, __shfl_xor(m, off));
    __shared__ float redm[4];
    __shared__ float reds[4];
    int wave = tid >> 6;
    if ((tid & 63) == 0) redm[wave] = m;
    __syncthreads();
    m = fmaxf(fmaxf(redm[0], redm[1]), fmaxf(redm[2], redm[3]));
    float e[4];
    float s = 0.f;
#pragma unroll
    for (int i = 0; i < 4; ++i) {
        int l = tid + 256 * i;
        e[i] = (l < valid) ? expf(v[i] - m) : 0.f;
        s += e[i];
    }
#pragma unroll
    for (int off = 1; off < 64; off <<= 1) s += __shfl_xor(s, off);
    if ((tid & 63) == 0) reds[wave] = s;
    __syncthreads();
    s = reds[0] + reds[1] + reds[2] + reds[3];
    float inv = 1.f / s;
#pragma unroll
    for (int i = 0; i < 4; ++i)
        out_probs[b * LL + tid + 256 * i] = e[i] * inv;
}

extern "C" void kernel_launch(void* const* d_in, const int* in_sizes, int n_in,
                              void* d_out, int out_size, void* d_ws, size_t ws_size,
                              hipStream_t stream) {
    const int*   obj_id         = (const int*)d_in[0];
    const int*   obj_size       = (const int*)d_in[1];
    const int*   cache_lines    = (const int*)d_in[2];
    const int*   lengths        = (const int*)d_in[3];
    const float* c0             = (const float*)d_in[4];
    const float* h0             = (const float*)d_in[5];
    const float* history        = (const float*)d_in[6];
    const float* obj_id_table   = (const float*)d_in[7];
    const float* obj_size_table = (const float*)d_in[8];
    const float* pos_table      = (const float*)d_in[9];
    const float* W_ih           = (const float*)d_in[10];
    const float* W_hh           = (const float*)d_in[11];
    const float* b_ih           = (const float*)d_in[12];
    const float* b_hh           = (const float*)d_in[13];
    const float* attn_W         = (const float*)d_in[14];
    const float* scorer_W       = (const float*)d_in[15];
    const float* scorer_b       = (const float*)d_in[16];
    const float* reuse_W        = (const float*)d_in[17];
    const float* reuse_b        = (const float*)d_in[18];

    float* out = (float*)d_out;
    float* out_probs = out;                 // (B, L)
    float* out_reuse = out + BB * LL;       // (B, L)

    char* ws = (char*)d_ws;
    float*          h_new  = (float*)(ws);                    // 64 KB
    unsigned short* hp     = (unsigned short*)(ws + 65536);   // 2 MB bf16
    float*          sv     = (float*)(ws + 65536 + 2097152);
    float*          rv     = (float*)(ws + 65536 + 2097152 + 32768);
    float*          xh_t   = (float*)(ws + 65536 + 2097152 + 65536);  // 112 KB
    float*          logits = (float*)(ws + 65536 + 2097152 + 65536);  // shares (disjoint lifetime)

    hipLaunchKernelGGL(embed_kernel, dim3(112), dim3(256), 0, stream,
                       obj_id, obj_size, h0, obj_id_table, obj_size_table, xh_t);
    hipLaunchKernelGGL(gates_kernel, dim3(HH), dim3(256), 0, stream,
                       xh_t, W_ih, W_hh, b_ih, b_hh, c0, h_new);
    hipLaunchKernelGGL(proj_kernel, dim3(BB * 16 + BB * 4), dim3(64), 0, stream,
                       history, h_new, attn_W, pos_table, scorer_W, reuse_W,
                       hp, sv, rv);
    hipLaunchKernelGGL(attn_kernel, dim3(BB * 8), dim3(256), 0, stream,
                       cache_lines, obj_id_table, hp, sv, rv,
                       scorer_b, reuse_b, logits, out_reuse);
    hipLaunchKernelGGL(finalsm_kernel, dim3(BB), dim3(256), 0, stream,
                       logits, lengths, out_probs);
}